// Round 17
// baseline (1448.673 us; speedup 1.0000x reference)
//
#include <hip/hip_runtime.h>
#include <cstdint>
#include <cstddef>

#define NN 4096
#define SS 64
#define EE 6
#define BN 64
#define KT 64
#define ITERS 10
#define NSG  128    // K-steps total

typedef _Float16 f16x8 __attribute__((ext_vector_type(8)));
typedef float f32x4 __attribute__((ext_vector_type(4)));

__device__ __forceinline__ float sigf(float x) { return 1.0f / (1.0f + __expf(-x)); }

// A fragment-major for 64-n tiles: [e][wt64][sg][q=quarter*2+pl][512]
__device__ __forceinline__ size_t cb64(int e, int wt, int sg, int q) {
    return ((((size_t)e * (NN / 64) + wt) * NSG + sg) * 8 + q) * 512;
}
// B fragment-major: [sg][st][pl][512]  (1MB, a permutation of hT)
__device__ __forceinline__ size_t bidx(int sg, int st, int pl) {
    return (((size_t)sg * 4 + st) * 2 + pl) * 512;
}
// fragment slot for h[n][s]
__device__ __forceinline__ size_t bslot(int n, int s, int pl) {
    const int sg = n >> 5, jo = n & 31;
    const int lane = ((jo >> 3) << 4) | (s & 15);
    return bidx(sg, s >> 4, pl) + (size_t)lane * 8 + (jo & 7);
}

// ---- k_init: h = x; B fragments (main) or row-major hT (fallback) ----
__global__ __launch_bounds__(256) void k_init(const float* __restrict__ x,
                                              float* __restrict__ h,
                                              _Float16* __restrict__ hTf,
                                              _Float16* __restrict__ hTh,
                                              _Float16* __restrict__ hTl) {
    const int t = threadIdx.x;
    const int n = blockIdx.x * 16 + (t & 15);
    const int c0 = (t >> 4) * 4;
    float4 v = *(const float4*)(x + (size_t)n * SS + c0);
    *(float4*)(h + (size_t)n * SS + c0) = v;
    const float vv[4] = {v.x, v.y, v.z, v.w};
#pragma unroll
    for (int k = 0; k < 4; k++) {
        _Float16 hi = (_Float16)vv[k];
        _Float16 lo = (_Float16)(vv[k] - (float)hi);
        if (hTf) {
            hTf[bslot(n, c0 + k, 0)] = hi;
            hTf[bslot(n, c0 + k, 1)] = lo;
        }
        if (hTh) {
            hTh[(size_t)(c0 + k) * NN + n] = hi;
            hTl[(size_t)(c0 + k) * NN + n] = lo;
        }
    }
}

// ---- K1 iteration-0 + pack fused (cb64 stores): fp32 edge scalar loads,
// hi/lo split in prefetch shadow, A-fragment stores; B from hTf.
// Values & MFMA order identical to k_act4w => bit-identical act.
__global__ __launch_bounds__(128, 4) void k_act_pack(const float* __restrict__ edge,
                                                     const _Float16* __restrict__ hTf,
                                                     float* __restrict__ act_part,
                                                     _Float16* __restrict__ eTf,
                                                     int jtot) {
    const int nt = blockIdx.x;        // 0..63 (64-n tile)
    const int e  = blockIdx.y;        // 0..5
    const int js = blockIdx.z;        // 0..jp-1
    const int tid = threadIdx.x;
    const int w   = tid >> 6;         // wave: rows nt*64 + w*32 .. +32
    const int lane = tid & 63;
    const int ln = lane & 15;
    const int lk = (lane >> 4) * 8;
    const int n0 = nt * 64 + w * 32;
    const int jbase = js * jtot;
    const int NSTEP = jtot / 32;      // 32 at jp=4
    const int sgbase = js * NSTEP;

    const float* A0 = edge + (size_t)e * NN * NN + (size_t)(jbase + lk) * NN + (n0 + ln);
    const float* A1 = A0 + 16;
    _Float16* stb0 = eTf + cb64(e, nt, sgbase, (w * 2 + 0) * 2) + (size_t)lane * 8;
    _Float16* stb1 = eTf + cb64(e, nt, sgbase, (w * 2 + 1) * 2) + (size_t)lane * 8;

    f32x4 acc[2][4];
#pragma unroll
    for (int nh = 0; nh < 2; nh++)
#pragma unroll
        for (int st = 0; st < 4; st++) acc[nh][st] = (f32x4)0.0f;

    f16x8 h0[2], l0[2], h1[2], l1[2];

#define LOADA(H, L, s_)                                                      \
    {                                                                        \
        const int sc = ((s_) < NSTEP) ? (s_) : 0;                            \
        const size_t off = (size_t)sc * 32 * NN;                             \
        float t0[8], t1[8];                                                  \
        _Pragma("unroll")                                                    \
        for (int i = 0; i < 8; i++) {                                        \
            t0[i] = A0[off + (size_t)i * NN];                                \
            t1[i] = A1[off + (size_t)i * NN];                                \
        }                                                                    \
        _Pragma("unroll")                                                    \
        for (int i = 0; i < 8; i++) {                                        \
            _Float16 hi0 = (_Float16)t0[i];                                  \
            H[0][i] = hi0;                                                   \
            L[0][i] = (_Float16)(t0[i] - (float)hi0);                        \
            _Float16 hi1 = (_Float16)t1[i];                                  \
            H[1][i] = hi1;                                                   \
            L[1][i] = (_Float16)(t1[i] - (float)hi1);                        \
        }                                                                    \
        _Float16* sp0 = stb0 + (size_t)sc * 4096;                            \
        *(f16x8*)(sp0)       = H[0];                                         \
        *(f16x8*)(sp0 + 512) = L[0];                                         \
        _Float16* sp1 = stb1 + (size_t)sc * 4096;                            \
        *(f16x8*)(sp1)       = H[1];                                         \
        *(f16x8*)(sp1 + 512) = L[1];                                         \
    }

#define COMPUTE(H, L, s)                                                     \
    {                                                                        \
        f16x8 bh[4], bl[4];                                                  \
        _Pragma("unroll")                                                    \
        for (int st = 0; st < 4; st++) {                                     \
            bh[st] = *(const f16x8*)(hTf + bidx(sgbase + (s), st, 0) + (size_t)lane * 8); \
            bl[st] = *(const f16x8*)(hTf + bidx(sgbase + (s), st, 1) + (size_t)lane * 8); \
        }                                                                    \
        _Pragma("unroll")                                                    \
        for (int nh = 0; nh < 2; nh++) {                                     \
            _Pragma("unroll")                                                \
            for (int st = 0; st < 4; st++) {                                 \
                acc[nh][st] = __builtin_amdgcn_mfma_f32_16x16x32_f16(        \
                    H[nh], bh[st], acc[nh][st], 0, 0, 0);                    \
                acc[nh][st] = __builtin_amdgcn_mfma_f32_16x16x32_f16(        \
                    H[nh], bl[st], acc[nh][st], 0, 0, 0);                    \
                acc[nh][st] = __builtin_amdgcn_mfma_f32_16x16x32_f16(        \
                    L[nh], bh[st], acc[nh][st], 0, 0, 0);                    \
            }                                                                \
        }                                                                    \
    }

    LOADA(h0, l0, 0);
    LOADA(h1, l1, 1);
    for (int s = 0; s < NSTEP; s += 2) {
        COMPUTE(h0, l0, s);     LOADA(h0, l0, s + 2);
        COMPUTE(h1, l1, s + 1); LOADA(h1, l1, s + 3);
    }
#undef LOADA
#undef COMPUTE

    float* ap = act_part + (size_t)(js * EE + e) * NN * SS;
#pragma unroll
    for (int nh = 0; nh < 2; nh++)
#pragma unroll
        for (int st = 0; st < 4; st++)
#pragma unroll
            for (int r = 0; r < 4; r++) {
                const int n = n0 + nh * 16 + (lane >> 4) * 4 + r;
                ap[(size_t)n * SS + st * 16 + ln] = acc[nh][st][r];
            }
}

// ---- K1 main (iterations 1+): 64n wave tile, ring-2 prefetch for BOTH A and B.
// B prefetched with A(s+2) so the pre-MFMA waitcnt leaves 2 full steps
// (32KB/wave) in flight. Values & MFMA order identical => bit-identical.
__global__ __launch_bounds__(64, 2) void k_act4w(const _Float16* __restrict__ eTf,
                                                 const _Float16* __restrict__ hTf,
                                                 float* __restrict__ act_part,
                                                 int jtot) {
    const int wt = blockIdx.x;        // 0..63 (64-n tiles)
    const int e  = blockIdx.y;        // 0..5
    const int js = blockIdx.z;        // 0..jp-1
    const int lane = threadIdx.x;
    const int ln = lane & 15;
    const int n0 = wt * 64;
    const int NSTEP = jtot / 32;      // 32 at jp=4
    const int sgbase = js * NSTEP;

    const _Float16* Abase = eTf + cb64(e, wt, sgbase, 0) + (size_t)lane * 8;

    f32x4 acc[4][4];
#pragma unroll
    for (int qt = 0; qt < 4; qt++)
#pragma unroll
        for (int st = 0; st < 4; st++) acc[qt][st] = (f32x4)0.0f;

    f16x8 H0[4], L0[4], H1[4], L1[4];
    f16x8 BH0[4], BL0[4], BH1[4], BL1[4];

#define LOADA(H, L, s_)                                                      \
    {                                                                        \
        const int sc = ((s_) < NSTEP) ? (s_) : 0;                            \
        const _Float16* p = Abase + (size_t)sc * 4096;                       \
        _Pragma("unroll")                                                    \
        for (int qt = 0; qt < 4; qt++) {                                     \
            H[qt] = *(const f16x8*)(p + qt * 1024);                          \
            L[qt] = *(const f16x8*)(p + qt * 1024 + 512);                    \
        }                                                                    \
    }

#define LOADB(BH, BL, s_)                                                    \
    {                                                                        \
        const int sc = ((s_) < NSTEP) ? (s_) : 0;                            \
        _Pragma("unroll")                                                    \
        for (int st = 0; st < 4; st++) {                                     \
            BH[st] = *(const f16x8*)(hTf + bidx(sgbase + sc, st, 0) + (size_t)lane * 8); \
            BL[st] = *(const f16x8*)(hTf + bidx(sgbase + sc, st, 1) + (size_t)lane * 8); \
        }                                                                    \
    }

#define COMPUTE(H, L, BH, BL)                                                \
    {                                                                        \
        _Pragma("unroll")                                                    \
        for (int qt = 0; qt < 4; qt++) {                                     \
            _Pragma("unroll")                                                \
            for (int st = 0; st < 4; st++) {                                 \
                acc[qt][st] = __builtin_amdgcn_mfma_f32_16x16x32_f16(        \
                    H[qt], BH[st], acc[qt][st], 0, 0, 0);                    \
                acc[qt][st] = __builtin_amdgcn_mfma_f32_16x16x32_f16(        \
                    H[qt], BL[st], acc[qt][st], 0, 0, 0);                    \
                acc[qt][st] = __builtin_amdgcn_mfma_f32_16x16x32_f16(        \
                    L[qt], BH[st], acc[qt][st], 0, 0, 0);                    \
            }                                                                \
        }                                                                    \
    }

    LOADA(H0, L0, 0); LOADB(BH0, BL0, 0);
    LOADA(H1, L1, 1); LOADB(BH1, BL1, 1);
    for (int s = 0; s < NSTEP; s += 2) {
        COMPUTE(H0, L0, BH0, BL0);
        LOADA(H0, L0, s + 2); LOADB(BH0, BL0, s + 2);
        COMPUTE(H1, L1, BH1, BL1);
        LOADA(H1, L1, s + 3); LOADB(BH1, BL1, s + 3);
    }
#undef LOADA
#undef LOADB
#undef COMPUTE

    float* ap = act_part + (size_t)(js * EE + e) * NN * SS;
#pragma unroll
    for (int qt = 0; qt < 4; qt++)
#pragma unroll
        for (int st = 0; st < 4; st++)
#pragma unroll
            for (int r = 0; r < 4; r++) {
                const int n = n0 + qt * 16 + (lane >> 4) * 4 + r;
                ap[(size_t)n * SS + st * 16 + ln] = acc[qt][st][r];
            }
}

// ---- K1 fallback (fp32 edge, load-time split, unpadded row-major hT) ----
__global__ __launch_bounds__(128, 4) void k_act_mfma(const float* __restrict__ edge,
                                                     const _Float16* __restrict__ hTh,
                                                     const _Float16* __restrict__ hTl,
                                                     float* __restrict__ act_part,
                                                     int jtot) {
    const int nt = blockIdx.x;
    const int e  = blockIdx.y;
    const int js = blockIdx.z;
    const int tid = threadIdx.x;
    const int w   = tid >> 6;
    const int lane = tid & 63;
    const int ln = lane & 15;
    const int lk = (lane >> 4) * 8;
    const int n0 = nt * 64 + w * 32;
    const int jbase = js * jtot;
    const int NSTEP = jtot / 32;

    const float* A0 = edge + (size_t)e * NN * NN + (size_t)(jbase + lk) * NN + (n0 + ln);
    const float* A1 = A0 + 16;
    const size_t bbase = (size_t)ln * NN + jbase + lk;

    f32x4 acc[2][4];
#pragma unroll
    for (int nh = 0; nh < 2; nh++)
#pragma unroll
        for (int st = 0; st < 4; st++) acc[nh][st] = (f32x4)0.0f;

    f16x8 h0[2], l0[2], h1[2], l1[2];

#define LOADA(H, L, s_)                                                      \
    {                                                                        \
        const int sc = ((s_) < NSTEP) ? (s_) : 0;                            \
        const size_t off = (size_t)sc * 32 * NN;                             \
        float t0[8], t1[8];                                                  \
        _Pragma("unroll")                                                    \
        for (int i = 0; i < 8; i++) {                                        \
            t0[i] = A0[off + (size_t)i * NN];                                \
            t1[i] = A1[off + (size_t)i * NN];                                \
        }                                                                    \
        _Pragma("unroll")                                                    \
        for (int i = 0; i < 8; i++) {                                        \
            _Float16 hi0 = (_Float16)t0[i];                                  \
            H[0][i] = hi0;                                                   \
            L[0][i] = (_Float16)(t0[i] - (float)hi0);                        \
            _Float16 hi1 = (_Float16)t1[i];                                  \
            H[1][i] = hi1;                                                   \
            L[1][i] = (_Float16)(t1[i] - (float)hi1);                        \
        }                                                                    \
    }

#define COMPUTE(H, L, s)                                                     \
    {                                                                        \
        f16x8 bh[4], bl[4];                                                  \
        _Pragma("unroll")                                                    \
        for (int st = 0; st < 4; st++) {                                     \
            const size_t bo = bbase + (size_t)st * 16 * NN + (size_t)(s) * 32;\
            bh[st] = *(const f16x8*)(hTh + bo);                              \
            bl[st] = *(const f16x8*)(hTl + bo);                              \
        }                                                                    \
        _Pragma("unroll")                                                    \
        for (int nh = 0; nh < 2; nh++) {                                     \
            _Pragma("unroll")                                                \
            for (int st = 0; st < 4; st++) {                                 \
                acc[nh][st] = __builtin_amdgcn_mfma_f32_16x16x32_f16(        \
                    H[nh], bh[st], acc[nh][st], 0, 0, 0);                    \
                acc[nh][st] = __builtin_amdgcn_mfma_f32_16x16x32_f16(        \
                    H[nh], bl[st], acc[nh][st], 0, 0, 0);                    \
                acc[nh][st] = __builtin_amdgcn_mfma_f32_16x16x32_f16(        \
                    L[nh], bh[st], acc[nh][st], 0, 0, 0);                    \
            }                                                                \
        }                                                                    \
    }

    LOADA(h0, l0, 0);
    LOADA(h1, l1, 1);
    for (int s = 0; s < NSTEP; s += 2) {
        COMPUTE(h0, l0, s);     LOADA(h0, l0, s + 2);
        COMPUTE(h1, l1, s + 1); LOADA(h1, l1, s + 3);
    }
#undef LOADA
#undef COMPUTE

    float* ap = act_part + (size_t)(js * EE + e) * NN * SS;
#pragma unroll
    for (int nh = 0; nh < 2; nh++)
#pragma unroll
        for (int st = 0; st < 4; st++)
#pragma unroll
            for (int r = 0; r < 4; r++) {
                const int n = n0 + nh * 16 + (lane >> 4) * 4 + r;
                ap[(size_t)n * SS + st * 16 + ln] = acc[nh][st][r];
            }
}

// ---- K1 fallback (fp32 VALU) for tiny ws ----
__global__ __launch_bounds__(128) void k_act(const float* __restrict__ edge,
                                             const float* __restrict__ h,
                                             float* __restrict__ act_part,
                                             int jtot) {
    __shared__ float hbuf[2][KT][SS];
    const int nb = blockIdx.x;
    const int e  = blockIdx.y;
    const int js = blockIdx.z;
    const int tid = threadIdx.x;
    const int ng = tid & 7;
    const int sg = tid >> 3;
    const int n0 = nb * BN;
    const int s0 = sg * 4;
    const int jbase = js * jtot;

    const float4* hsrc4 = (const float4*)(h + (size_t)jbase * SS);

    float acc[8][4];
#pragma unroll
    for (int i = 0; i < 8; i++)
#pragma unroll
        for (int k = 0; k < 4; k++) acc[i][k] = 0.0f;

    float4 pre[8];
#pragma unroll
    for (int r = 0; r < 8; r++) pre[r] = hsrc4[r * 128 + tid];
    {
        float4* dst = (float4*)&hbuf[0][0][0];
#pragma unroll
        for (int r = 0; r < 8; r++) dst[r * 128 + tid] = pre[r];
    }
    __syncthreads();

    const float* eg = edge + (size_t)e * NN * NN + (size_t)jbase * NN + n0 + ng * 8;

    float4 ea[4][2];
#pragma unroll
    for (int u = 0; u < 4; u++) {
        ea[u][0] = *(const float4*)(eg + (size_t)u * NN);
        ea[u][1] = *(const float4*)(eg + (size_t)u * NN + 4);
    }

    const int NCH = jtot / KT;
    for (int c = 0; c < NCH; c++) {
        if (c + 1 < NCH) {
#pragma unroll
            for (int r = 0; r < 8; r++) pre[r] = hsrc4[(c + 1) * (KT * SS / 4) + r * 128 + tid];
        }
        const float (*hb)[SS] = hbuf[c & 1];
        for (int jj = 0; jj < KT; jj += 4) {
            const int q = c * KT + jj + 4;
            const float* pe = eg + (size_t)(q < jtot ? q : 0) * NN;
            float4 eb[4][2];
#pragma unroll
            for (int u = 0; u < 4; u++) {
                eb[u][0] = *(const float4*)(pe + (size_t)u * NN);
                eb[u][1] = *(const float4*)(pe + (size_t)u * NN + 4);
            }
#pragma unroll
            for (int u = 0; u < 4; u++) {
                const float4 hv = *(const float4*)&hb[jj + u][s0];
                const float ev[8] = {ea[u][0].x, ea[u][0].y, ea[u][0].z, ea[u][0].w,
                                     ea[u][1].x, ea[u][1].y, ea[u][1].z, ea[u][1].w};
#pragma unroll
                for (int i = 0; i < 8; i++) {
                    acc[i][0] += ev[i] * hv.x;
                    acc[i][1] += ev[i] * hv.y;
                    acc[i][2] += ev[i] * hv.z;
                    acc[i][3] += ev[i] * hv.w;
                }
            }
#pragma unroll
            for (int u = 0; u < 4; u++) { ea[u][0] = eb[u][0]; ea[u][1] = eb[u][1]; }
        }
        if (c + 1 < NCH) {
            float4* dst = (float4*)&hbuf[(c + 1) & 1][0][0];
#pragma unroll
            for (int r = 0; r < 8; r++) dst[r * 128 + tid] = pre[r];
        }
        __syncthreads();
    }

    float* ap = act_part + (((size_t)js * EE + e) * NN + n0 + ng * 8) * SS + s0;
#pragma unroll
    for (int i = 0; i < 8; i++)
        *(float4*)(ap + (size_t)i * SS) = make_float4(acc[i][0], acc[i][1], acc[i][2], acc[i][3]);
}

// ---- K2: LDS-staged W; gates; in-place h; B-fragment (or row-major) regen ----
__global__ __launch_bounds__(256) void k_update(const float* __restrict__ act_part,
                                                float* __restrict__ h,            // in/out
                                                const float* __restrict__ W,      // [E][S][3S]
                                                const float* __restrict__ uz_ur,  // [S][2S]
                                                const float* __restrict__ uh,     // [S][S]
                                                const float* __restrict__ ba,     // [S]
                                                _Float16* __restrict__ hTf,
                                                _Float16* __restrict__ hTh,
                                                _Float16* __restrict__ hTl,
                                                int jparts) {
    __shared__ float w_lds[SS][192];      // 48KB
    __shared__ float a_lds[16][68];
    __shared__ float h_lds[16][68];
    __shared__ float zrh_lds[16][196];
    __shared__ float uzr_lds[16][132];
    __shared__ float rh_lds[16][68];

    const int n0 = blockIdx.x * 16;
    const int t = threadIdx.x;
    const int nl = t & 15;
    const int kg = t >> 4;

    {
        const int row = t >> 4, c4 = t & 15;
        float4 v = *(const float4*)(h + (size_t)(n0 + row) * SS + c4 * 4);
        *(float4*)&h_lds[row][c4 * 4] = v;
    }

    float zacc[12];
#pragma unroll
    for (int k = 0; k < 12; k++) zacc[k] = 0.0f;
    const int k0 = kg * 12;

    for (int e = 0; e < EE; e++) {
        __syncthreads();
        {
            const float4* wsrc = (const float4*)(W + (size_t)e * SS * 192);
            float4* wdst = (float4*)&w_lds[0][0];
#pragma unroll
            for (int r = 0; r < 12; r++) wdst[r * 256 + t] = wsrc[r * 256 + t];
        }
        {
            const int row = t >> 4, c4 = t & 15;
            const size_t base = ((size_t)e * NN + (n0 + row)) * SS + c4 * 4;
            float4 bv = *(const float4*)(ba + c4 * 4);
            float vx = bv.x, vy = bv.y, vz = bv.z, vw = bv.w;
            for (int p = 0; p < jparts; p++) {
                float4 pp = *(const float4*)(act_part + base + (size_t)p * EE * NN * SS);
                vx += pp.x; vy += pp.y; vz += pp.z; vw += pp.w;
            }
            *(float4*)&a_lds[row][c4 * 4] = make_float4(vx, vy, vz, vw);
        }
        __syncthreads();
#pragma unroll 8
        for (int s = 0; s < SS; s++) {
            const float av = a_lds[nl][s];
            const float4* wrow = (const float4*)&w_lds[s][k0];
            const float4 w0 = wrow[0], w1 = wrow[1], w2 = wrow[2];
            zacc[0] += av * w0.x; zacc[1] += av * w0.y; zacc[2]  += av * w0.z; zacc[3]  += av * w0.w;
            zacc[4] += av * w1.x; zacc[5] += av * w1.y; zacc[6]  += av * w1.z; zacc[7]  += av * w1.w;
            zacc[8] += av * w2.x; zacc[9] += av * w2.y; zacc[10] += av * w2.z; zacc[11] += av * w2.w;
        }
    }

    float uacc[8];
#pragma unroll
    for (int k = 0; k < 8; k++) uacc[k] = 0.0f;
#pragma unroll 4
    for (int j = 0; j < SS; j++) {
        const float hv = h_lds[nl][j];
        const float4* urow = (const float4*)(uz_ur + (size_t)j * 128 + kg * 8);
        const float4 u0 = urow[0], u1 = urow[1];
        uacc[0] += hv * u0.x; uacc[1] += hv * u0.y; uacc[2] += hv * u0.z; uacc[3] += hv * u0.w;
        uacc[4] += hv * u1.x; uacc[5] += hv * u1.y; uacc[6] += hv * u1.z; uacc[7] += hv * u1.w;
    }

    *(float4*)&zrh_lds[nl][k0]     = make_float4(zacc[0], zacc[1], zacc[2], zacc[3]);
    *(float4*)&zrh_lds[nl][k0 + 4] = make_float4(zacc[4], zacc[5], zacc[6], zacc[7]);
    *(float4*)&zrh_lds[nl][k0 + 8] = make_float4(zacc[8], zacc[9], zacc[10], zacc[11]);
    *(float4*)&uzr_lds[nl][kg * 8]     = make_float4(uacc[0], uacc[1], uacc[2], uacc[3]);
    *(float4*)&uzr_lds[nl][kg * 8 + 4] = make_float4(uacc[4], uacc[5], uacc[6], uacc[7]);
    __syncthreads();

    const int sg4 = kg * 4;
    const float4 wz = *(const float4*)&zrh_lds[nl][sg4];
    const float4 wr = *(const float4*)&zrh_lds[nl][64 + sg4];
    const float4 wh = *(const float4*)&zrh_lds[nl][128 + sg4];
    const float4 uz = *(const float4*)&uzr_lds[nl][sg4];
    const float4 ur = *(const float4*)&uzr_lds[nl][64 + sg4];
    const float4 hv4 = *(const float4*)&h_lds[nl][sg4];

    float z4[4], rh4[4];
    {
        const float wzv[4] = {wz.x, wz.y, wz.z, wz.w};
        const float wrv[4] = {wr.x, wr.y, wr.z, wr.w};
        const float uzv[4] = {uz.x, uz.y, uz.z, uz.w};
        const float urv[4] = {ur.x, ur.y, ur.z, ur.w};
        const float hvv[4] = {hv4.x, hv4.y, hv4.z, hv4.w};
#pragma unroll
        for (int k = 0; k < 4; k++) {
            z4[k] = sigf(wzv[k] + uzv[k]);
            const float r = sigf(wrv[k] + urv[k]);
            rh4[k] = r * hvv[k];
        }
    }
    *(float4*)&rh_lds[nl][sg4] = make_float4(rh4[0], rh4[1], rh4[2], rh4[3]);
    __syncthreads();

    float hacc[4];
#pragma unroll
    for (int k = 0; k < 4; k++) hacc[k] = 0.0f;
#pragma unroll 4
    for (int j = 0; j < SS; j++) {
        const float rhv = rh_lds[nl][j];
        const float4 u = *(const float4*)(uh + (size_t)j * SS + sg4);
        hacc[0] += rhv * u.x; hacc[1] += rhv * u.y; hacc[2] += rhv * u.z; hacc[3] += rhv * u.w;
    }

    {
        const float whv[4] = {wh.x, wh.y, wh.z, wh.w};
        const float hvv[4] = {hv4.x, hv4.y, hv4.z, hv4.w};
        float ov[4];
#pragma unroll
        for (int k = 0; k < 4; k++) {
            const float hh = tanhf(whv[k] + hacc[k]);
            ov[k] = (1.0f - z4[k]) * hvv[k] + z4[k] * hh;
        }
        const int n = n0 + nl;
        *(float4*)(h + (size_t)n * SS + sg4) = make_float4(ov[0], ov[1], ov[2], ov[3]);
#pragma unroll
        for (int k = 0; k < 4; k++) {
            _Float16 hi = (_Float16)ov[k];
            _Float16 lo = (_Float16)(ov[k] - (float)hi);
            if (hTf) {
                hTf[bslot(n, sg4 + k, 0)] = hi;
                hTf[bslot(n, sg4 + k, 1)] = lo;
            }
            if (hTh) {
                hTh[(size_t)(sg4 + k) * NN + n] = hi;
                hTl[(size_t)(sg4 + k) * NN + n] = lo;
            }
        }
    }
}

extern "C" void kernel_launch(void* const* d_in, const int* in_sizes, int n_in,
                              void* d_out, int out_size, void* d_ws, size_t ws_size,
                              hipStream_t stream) {
    const float* x    = (const float*)d_in[0];
    const float* edge = (const float*)d_in[1];
    const float* ba   = (const float*)d_in[2];
    const float* W    = (const float*)d_in[3];
    const float* uzur = (const float*)d_in[4];
    const float* uh   = (const float*)d_in[5];

    float* h = (float*)d_out;
    char*  wsb = (char*)d_ws;

    const size_t actB = (size_t)EE * NN * SS * sizeof(float);        // 6.29 MB
    const size_t hTfB = (size_t)NSG * 4 * 2 * 512 * sizeof(_Float16);// 1.0 MB (B fragments)
    const size_t hTBu = (size_t)SS * NN * sizeof(_Float16) * 2;      // 1.0 MB (fallback row-major)
    const size_t eTfB = (size_t)EE * NN * NN * 2 * sizeof(_Float16); // 402.7 MB
    const int jp = 4;
    const size_t needFull = eTfB + (size_t)jp * actB + hTfB;         // ~429 MB

    if (ws_size >= needFull) {
        _Float16* eTf = (_Float16*)wsb;
        float*    act = (float*)(wsb + eTfB);
        _Float16* hTf = (_Float16*)(wsb + eTfB + (size_t)jp * actB);
        const int jtot = NN / jp;

        k_init<<<NN / 16, 256, 0, stream>>>(x, h, hTf, nullptr, nullptr);

        // it = 0: act + pack fused (fp32 edge reads, writes 64n-tile eTf fragments)
        k_act_pack<<<dim3(NN / 64, EE, jp), 128, 0, stream>>>(edge, hTf, act, eTf, jtot);
        k_update<<<NN / 16, 256, 0, stream>>>(act, h, W, uzur, uh, ba, hTf, nullptr, nullptr, jp);

        for (int it = 1; it < ITERS; ++it) {
            k_act4w<<<dim3(NN / 64, EE, jp), 64, 0, stream>>>(eTf, hTf, act, jtot);
            k_update<<<NN / 16, 256, 0, stream>>>(act, h, W, uzur, uh, ba, hTf, nullptr, nullptr, jp);
        }
    } else {
        int jp2;
        bool use_mfma;
        if      (ws_size >= 4 * actB + hTBu) { jp2 = 4; use_mfma = true;  }
        else if (ws_size >= 2 * actB + hTBu) { jp2 = 2; use_mfma = true;  }
        else if (ws_size >= 1 * actB + hTBu) { jp2 = 1; use_mfma = true;  }
        else                                 { jp2 = 1; use_mfma = false; }

        float*     act = (float*)wsb;
        _Float16*  hTh = use_mfma ? (_Float16*)(wsb + (size_t)jp2 * actB) : nullptr;
        _Float16*  hTl = use_mfma ? (_Float16*)(wsb + (size_t)jp2 * actB) + (size_t)SS * NN : nullptr;
        const int jtot = NN / jp2;

        k_init<<<NN / 16, 256, 0, stream>>>(x, h, nullptr, hTh, hTl);
        for (int it = 0; it < ITERS; ++it) {
            if (use_mfma) {
                k_act_mfma<<<dim3(NN / 64, EE, jp2), 128, 0, stream>>>(edge, hTh, hTl, act, jtot);
            } else {
                k_act<<<dim3(NN / BN, EE, jp2), 128, 0, stream>>>(edge, h, act, jtot);
            }
            k_update<<<NN / 16, 256, 0, stream>>>(act, h, W, uzur, uh, ba, nullptr, hTh, hTl, jp2);
        }
    }
}

// Round 18
// 1419.696 us; speedup vs baseline: 1.0204x; 1.0204x over previous
//
#include <hip/hip_runtime.h>
#include <cstdint>
#include <cstddef>

#define NN 4096
#define SS 64
#define EE 6
#define BN 64
#define KT 64
#define ITERS 10
#define NSG  128    // K-steps total

typedef _Float16 f16x8 __attribute__((ext_vector_type(8)));
typedef float f32x4 __attribute__((ext_vector_type(4)));

__device__ __forceinline__ float sigf(float x) { return 1.0f / (1.0f + __expf(-x)); }

// A fragment-major for 64-n tiles: [e][wt64][sg][q=quarter*2+pl][512]
// -> one 64-n wave's A stream is fully contiguous: 8KB/step, 256KB total.
__device__ __forceinline__ size_t cb64(int e, int wt, int sg, int q) {
    return ((((size_t)e * (NN / 64) + wt) * NSG + sg) * 8 + q) * 512;
}
// B fragment-major: [sg][st][pl][512]  (1MB, a permutation of hT)
__device__ __forceinline__ size_t bidx(int sg, int st, int pl) {
    return (((size_t)sg * 4 + st) * 2 + pl) * 512;
}
// fragment slot for h[n][s]
__device__ __forceinline__ size_t bslot(int n, int s, int pl) {
    const int sg = n >> 5, jo = n & 31;
    const int lane = ((jo >> 3) << 4) | (s & 15);
    return bidx(sg, s >> 4, pl) + (size_t)lane * 8 + (jo & 7);
}

// ---- k_init: h = x; B fragments (main) or row-major hT (fallback) ----
__global__ __launch_bounds__(256) void k_init(const float* __restrict__ x,
                                              float* __restrict__ h,
                                              _Float16* __restrict__ hTf,
                                              _Float16* __restrict__ hTh,
                                              _Float16* __restrict__ hTl) {
    const int t = threadIdx.x;
    const int n = blockIdx.x * 16 + (t & 15);
    const int c0 = (t >> 4) * 4;
    float4 v = *(const float4*)(x + (size_t)n * SS + c0);
    *(float4*)(h + (size_t)n * SS + c0) = v;
    const float vv[4] = {v.x, v.y, v.z, v.w};
#pragma unroll
    for (int k = 0; k < 4; k++) {
        _Float16 hi = (_Float16)vv[k];
        _Float16 lo = (_Float16)(vv[k] - (float)hi);
        if (hTf) {
            hTf[bslot(n, c0 + k, 0)] = hi;
            hTf[bslot(n, c0 + k, 1)] = lo;
        }
        if (hTh) {
            hTh[(size_t)(c0 + k) * NN + n] = hi;
            hTl[(size_t)(c0 + k) * NN + n] = lo;
        }
    }
}

// ---- K1 iteration-0 + pack fused (cb64 stores): fp32 edge scalar loads,
// hi/lo split in prefetch shadow, A-fragment stores; B from hTf.
// Values & MFMA order identical to k_act4w => bit-identical act.
__global__ __launch_bounds__(128, 4) void k_act_pack(const float* __restrict__ edge,
                                                     const _Float16* __restrict__ hTf,
                                                     float* __restrict__ act_part,
                                                     _Float16* __restrict__ eTf,
                                                     int jtot) {
    const int nt = blockIdx.x;        // 0..63 (64-n tile)
    const int e  = blockIdx.y;        // 0..5
    const int js = blockIdx.z;        // 0..jp-1
    const int tid = threadIdx.x;
    const int w   = tid >> 6;         // wave: rows nt*64 + w*32 .. +32
    const int lane = tid & 63;
    const int ln = lane & 15;
    const int lk = (lane >> 4) * 8;
    const int n0 = nt * 64 + w * 32;
    const int jbase = js * jtot;
    const int NSTEP = jtot / 32;      // 32 at jp=4
    const int sgbase = js * NSTEP;

    const float* A0 = edge + (size_t)e * NN * NN + (size_t)(jbase + lk) * NN + (n0 + ln);
    const float* A1 = A0 + 16;
    _Float16* stb0 = eTf + cb64(e, nt, sgbase, (w * 2 + 0) * 2) + (size_t)lane * 8;
    _Float16* stb1 = eTf + cb64(e, nt, sgbase, (w * 2 + 1) * 2) + (size_t)lane * 8;

    f32x4 acc[2][4];
#pragma unroll
    for (int nh = 0; nh < 2; nh++)
#pragma unroll
        for (int st = 0; st < 4; st++) acc[nh][st] = (f32x4)0.0f;

    f16x8 h0[2], l0[2], h1[2], l1[2];

#define LOADA(H, L, s_)                                                      \
    {                                                                        \
        const int sc = ((s_) < NSTEP) ? (s_) : 0;                            \
        const size_t off = (size_t)sc * 32 * NN;                             \
        float t0[8], t1[8];                                                  \
        _Pragma("unroll")                                                    \
        for (int i = 0; i < 8; i++) {                                        \
            t0[i] = A0[off + (size_t)i * NN];                                \
            t1[i] = A1[off + (size_t)i * NN];                                \
        }                                                                    \
        _Pragma("unroll")                                                    \
        for (int i = 0; i < 8; i++) {                                        \
            _Float16 hi0 = (_Float16)t0[i];                                  \
            H[0][i] = hi0;                                                   \
            L[0][i] = (_Float16)(t0[i] - (float)hi0);                        \
            _Float16 hi1 = (_Float16)t1[i];                                  \
            H[1][i] = hi1;                                                   \
            L[1][i] = (_Float16)(t1[i] - (float)hi1);                        \
        }                                                                    \
        _Float16* sp0 = stb0 + (size_t)sc * 4096;                            \
        *(f16x8*)(sp0)       = H[0];                                         \
        *(f16x8*)(sp0 + 512) = L[0];                                         \
        _Float16* sp1 = stb1 + (size_t)sc * 4096;                            \
        *(f16x8*)(sp1)       = H[1];                                         \
        *(f16x8*)(sp1 + 512) = L[1];                                         \
    }

#define COMPUTE(H, L, s)                                                     \
    {                                                                        \
        f16x8 bh[4], bl[4];                                                  \
        _Pragma("unroll")                                                    \
        for (int st = 0; st < 4; st++) {                                     \
            bh[st] = *(const f16x8*)(hTf + bidx(sgbase + (s), st, 0) + (size_t)lane * 8); \
            bl[st] = *(const f16x8*)(hTf + bidx(sgbase + (s), st, 1) + (size_t)lane * 8); \
        }                                                                    \
        _Pragma("unroll")                                                    \
        for (int nh = 0; nh < 2; nh++) {                                     \
            _Pragma("unroll")                                                \
            for (int st = 0; st < 4; st++) {                                 \
                acc[nh][st] = __builtin_amdgcn_mfma_f32_16x16x32_f16(        \
                    H[nh], bh[st], acc[nh][st], 0, 0, 0);                    \
                acc[nh][st] = __builtin_amdgcn_mfma_f32_16x16x32_f16(        \
                    H[nh], bl[st], acc[nh][st], 0, 0, 0);                    \
                acc[nh][st] = __builtin_amdgcn_mfma_f32_16x16x32_f16(        \
                    L[nh], bh[st], acc[nh][st], 0, 0, 0);                    \
            }                                                                \
        }                                                                    \
    }

    LOADA(h0, l0, 0);
    LOADA(h1, l1, 1);
    for (int s = 0; s < NSTEP; s += 2) {
        COMPUTE(h0, l0, s);     LOADA(h0, l0, s + 2);
        COMPUTE(h1, l1, s + 1); LOADA(h1, l1, s + 3);
    }
#undef LOADA
#undef COMPUTE

    float* ap = act_part + (size_t)(js * EE + e) * NN * SS;
#pragma unroll
    for (int nh = 0; nh < 2; nh++)
#pragma unroll
        for (int st = 0; st < 4; st++)
#pragma unroll
            for (int r = 0; r < 4; r++) {
                const int n = n0 + nh * 16 + (lane >> 4) * 4 + r;
                ap[(size_t)n * SS + st * 16 + ln] = acc[nh][st][r];
            }
}

// ---- K1 main (iterations 1+): 64n wave tile. A 8KB/step contiguous; B 8KB/step
// from L2-resident hTf -> B:A = 1:1. 48 MFMA/step.
// Per-accumulator MFMA sequence identical to k_act_pack => bit-identical.
__global__ __launch_bounds__(64, 2) void k_act4w(const _Float16* __restrict__ eTf,
                                                 const _Float16* __restrict__ hTf,
                                                 float* __restrict__ act_part,
                                                 int jtot) {
    const int wt = blockIdx.x;        // 0..63 (64-n tiles)
    const int e  = blockIdx.y;        // 0..5
    const int js = blockIdx.z;        // 0..jp-1
    const int lane = threadIdx.x;
    const int ln = lane & 15;
    const int n0 = wt * 64;
    const int NSTEP = jtot / 32;      // 32 at jp=4
    const int sgbase = js * NSTEP;

    const _Float16* Abase = eTf + cb64(e, wt, sgbase, 0) + (size_t)lane * 8;

    f32x4 acc[4][4];
#pragma unroll
    for (int qt = 0; qt < 4; qt++)
#pragma unroll
        for (int st = 0; st < 4; st++) acc[qt][st] = (f32x4)0.0f;

    f16x8 H0[4], L0[4], H1[4], L1[4];

#define LOADA(H, L, s_)                                                      \
    {                                                                        \
        const int sc = ((s_) < NSTEP) ? (s_) : 0;                            \
        const _Float16* p = Abase + (size_t)sc * 4096;                       \
        _Pragma("unroll")                                                    \
        for (int qt = 0; qt < 4; qt++) {                                     \
            H[qt] = *(const f16x8*)(p + qt * 1024);                          \
            L[qt] = *(const f16x8*)(p + qt * 1024 + 512);                    \
        }                                                                    \
    }

#define COMPUTE(H, L, s)                                                     \
    {                                                                        \
        f16x8 bh[4], bl[4];                                                  \
        _Pragma("unroll")                                                    \
        for (int st = 0; st < 4; st++) {                                     \
            bh[st] = *(const f16x8*)(hTf + bidx(sgbase + (s), st, 0) + (size_t)lane * 8); \
            bl[st] = *(const f16x8*)(hTf + bidx(sgbase + (s), st, 1) + (size_t)lane * 8); \
        }                                                                    \
        _Pragma("unroll")                                                    \
        for (int qt = 0; qt < 4; qt++) {                                     \
            _Pragma("unroll")                                                \
            for (int st = 0; st < 4; st++) {                                 \
                acc[qt][st] = __builtin_amdgcn_mfma_f32_16x16x32_f16(        \
                    H[qt], bh[st], acc[qt][st], 0, 0, 0);                    \
                acc[qt][st] = __builtin_amdgcn_mfma_f32_16x16x32_f16(        \
                    H[qt], bl[st], acc[qt][st], 0, 0, 0);                    \
                acc[qt][st] = __builtin_amdgcn_mfma_f32_16x16x32_f16(        \
                    L[qt], bh[st], acc[qt][st], 0, 0, 0);                    \
            }                                                                \
        }                                                                    \
    }

    LOADA(H0, L0, 0);
    LOADA(H1, L1, 1);
    for (int s = 0; s < NSTEP; s += 2) {
        COMPUTE(H0, L0, s);     LOADA(H0, L0, s + 2);
        COMPUTE(H1, L1, s + 1); LOADA(H1, L1, s + 3);
    }
#undef LOADA
#undef COMPUTE

    float* ap = act_part + (size_t)(js * EE + e) * NN * SS;
#pragma unroll
    for (int qt = 0; qt < 4; qt++)
#pragma unroll
        for (int st = 0; st < 4; st++)
#pragma unroll
            for (int r = 0; r < 4; r++) {
                const int n = n0 + qt * 16 + (lane >> 4) * 4 + r;
                ap[(size_t)n * SS + st * 16 + ln] = acc[qt][st][r];
            }
}

// ---- K1 fallback (fp32 edge, load-time split, unpadded row-major hT) ----
__global__ __launch_bounds__(128, 4) void k_act_mfma(const float* __restrict__ edge,
                                                     const _Float16* __restrict__ hTh,
                                                     const _Float16* __restrict__ hTl,
                                                     float* __restrict__ act_part,
                                                     int jtot) {
    const int nt = blockIdx.x;
    const int e  = blockIdx.y;
    const int js = blockIdx.z;
    const int tid = threadIdx.x;
    const int w   = tid >> 6;
    const int lane = tid & 63;
    const int ln = lane & 15;
    const int lk = (lane >> 4) * 8;
    const int n0 = nt * 64 + w * 32;
    const int jbase = js * jtot;
    const int NSTEP = jtot / 32;

    const float* A0 = edge + (size_t)e * NN * NN + (size_t)(jbase + lk) * NN + (n0 + ln);
    const float* A1 = A0 + 16;
    const size_t bbase = (size_t)ln * NN + jbase + lk;

    f32x4 acc[2][4];
#pragma unroll
    for (int nh = 0; nh < 2; nh++)
#pragma unroll
        for (int st = 0; st < 4; st++) acc[nh][st] = (f32x4)0.0f;

    f16x8 h0[2], l0[2], h1[2], l1[2];

#define LOADA(H, L, s_)                                                      \
    {                                                                        \
        const int sc = ((s_) < NSTEP) ? (s_) : 0;                            \
        const size_t off = (size_t)sc * 32 * NN;                             \
        float t0[8], t1[8];                                                  \
        _Pragma("unroll")                                                    \
        for (int i = 0; i < 8; i++) {                                        \
            t0[i] = A0[off + (size_t)i * NN];                                \
            t1[i] = A1[off + (size_t)i * NN];                                \
        }                                                                    \
        _Pragma("unroll")                                                    \
        for (int i = 0; i < 8; i++) {                                        \
            _Float16 hi0 = (_Float16)t0[i];                                  \
            H[0][i] = hi0;                                                   \
            L[0][i] = (_Float16)(t0[i] - (float)hi0);                        \
            _Float16 hi1 = (_Float16)t1[i];                                  \
            H[1][i] = hi1;                                                   \
            L[1][i] = (_Float16)(t1[i] - (float)hi1);                        \
        }                                                                    \
    }

#define COMPUTE(H, L, s)                                                     \
    {                                                                        \
        f16x8 bh[4], bl[4];                                                  \
        _Pragma("unroll")                                                    \
        for (int st = 0; st < 4; st++) {                                     \
            const size_t bo = bbase + (size_t)st * 16 * NN + (size_t)(s) * 32;\
            bh[st] = *(const f16x8*)(hTh + bo);                              \
            bl[st] = *(const f16x8*)(hTl + bo);                              \
        }                                                                    \
        _Pragma("unroll")                                                    \
        for (int nh = 0; nh < 2; nh++) {                                     \
            _Pragma("unroll")                                                \
            for (int st = 0; st < 4; st++) {                                 \
                acc[nh][st] = __builtin_amdgcn_mfma_f32_16x16x32_f16(        \
                    H[nh], bh[st], acc[nh][st], 0, 0, 0);                    \
                acc[nh][st] = __builtin_amdgcn_mfma_f32_16x16x32_f16(        \
                    H[nh], bl[st], acc[nh][st], 0, 0, 0);                    \
                acc[nh][st] = __builtin_amdgcn_mfma_f32_16x16x32_f16(        \
                    L[nh], bh[st], acc[nh][st], 0, 0, 0);                    \
            }                                                                \
        }                                                                    \
    }

    LOADA(h0, l0, 0);
    LOADA(h1, l1, 1);
    for (int s = 0; s < NSTEP; s += 2) {
        COMPUTE(h0, l0, s);     LOADA(h0, l0, s + 2);
        COMPUTE(h1, l1, s + 1); LOADA(h1, l1, s + 3);
    }
#undef LOADA
#undef COMPUTE

    float* ap = act_part + (size_t)(js * EE + e) * NN * SS;
#pragma unroll
    for (int nh = 0; nh < 2; nh++)
#pragma unroll
        for (int st = 0; st < 4; st++)
#pragma unroll
            for (int r = 0; r < 4; r++) {
                const int n = n0 + nh * 16 + (lane >> 4) * 4 + r;
                ap[(size_t)n * SS + st * 16 + ln] = acc[nh][st][r];
            }
}

// ---- K1 fallback (fp32 VALU) for tiny ws ----
__global__ __launch_bounds__(128) void k_act(const float* __restrict__ edge,
                                             const float* __restrict__ h,
                                             float* __restrict__ act_part,
                                             int jtot) {
    __shared__ float hbuf[2][KT][SS];
    const int nb = blockIdx.x;
    const int e  = blockIdx.y;
    const int js = blockIdx.z;
    const int tid = threadIdx.x;
    const int ng = tid & 7;
    const int sg = tid >> 3;
    const int n0 = nb * BN;
    const int s0 = sg * 4;
    const int jbase = js * jtot;

    const float4* hsrc4 = (const float4*)(h + (size_t)jbase * SS);

    float acc[8][4];
#pragma unroll
    for (int i = 0; i < 8; i++)
#pragma unroll
        for (int k = 0; k < 4; k++) acc[i][k] = 0.0f;

    float4 pre[8];
#pragma unroll
    for (int r = 0; r < 8; r++) pre[r] = hsrc4[r * 128 + tid];
    {
        float4* dst = (float4*)&hbuf[0][0][0];
#pragma unroll
        for (int r = 0; r < 8; r++) dst[r * 128 + tid] = pre[r];
    }
    __syncthreads();

    const float* eg = edge + (size_t)e * NN * NN + (size_t)jbase * NN + n0 + ng * 8;

    float4 ea[4][2];
#pragma unroll
    for (int u = 0; u < 4; u++) {
        ea[u][0] = *(const float4*)(eg + (size_t)u * NN);
        ea[u][1] = *(const float4*)(eg + (size_t)u * NN + 4);
    }

    const int NCH = jtot / KT;
    for (int c = 0; c < NCH; c++) {
        if (c + 1 < NCH) {
#pragma unroll
            for (int r = 0; r < 8; r++) pre[r] = hsrc4[(c + 1) * (KT * SS / 4) + r * 128 + tid];
        }
        const float (*hb)[SS] = hbuf[c & 1];
        for (int jj = 0; jj < KT; jj += 4) {
            const int q = c * KT + jj + 4;
            const float* pe = eg + (size_t)(q < jtot ? q : 0) * NN;
            float4 eb[4][2];
#pragma unroll
            for (int u = 0; u < 4; u++) {
                eb[u][0] = *(const float4*)(pe + (size_t)u * NN);
                eb[u][1] = *(const float4*)(pe + (size_t)u * NN + 4);
            }
#pragma unroll
            for (int u = 0; u < 4; u++) {
                const float4 hv = *(const float4*)&hb[jj + u][s0];
                const float ev[8] = {ea[u][0].x, ea[u][0].y, ea[u][0].z, ea[u][0].w,
                                     ea[u][1].x, ea[u][1].y, ea[u][1].z, ea[u][1].w};
#pragma unroll
                for (int i = 0; i < 8; i++) {
                    acc[i][0] += ev[i] * hv.x;
                    acc[i][1] += ev[i] * hv.y;
                    acc[i][2] += ev[i] * hv.z;
                    acc[i][3] += ev[i] * hv.w;
                }
            }
#pragma unroll
            for (int u = 0; u < 4; u++) { ea[u][0] = eb[u][0]; ea[u][1] = eb[u][1]; }
        }
        if (c + 1 < NCH) {
            float4* dst = (float4*)&hbuf[(c + 1) & 1][0][0];
#pragma unroll
            for (int r = 0; r < 8; r++) dst[r * 128 + tid] = pre[r];
        }
        __syncthreads();
    }

    float* ap = act_part + (((size_t)js * EE + e) * NN + n0 + ng * 8) * SS + s0;
#pragma unroll
    for (int i = 0; i < 8; i++)
        *(float4*)(ap + (size_t)i * SS) = make_float4(acc[i][0], acc[i][1], acc[i][2], acc[i][3]);
}

// ---- K2: LDS-staged W; gates; in-place h; B-fragment (or row-major) regen ----
__global__ __launch_bounds__(256) void k_update(const float* __restrict__ act_part,
                                                float* __restrict__ h,            // in/out
                                                const float* __restrict__ W,      // [E][S][3S]
                                                const float* __restrict__ uz_ur,  // [S][2S]
                                                const float* __restrict__ uh,     // [S][S]
                                                const float* __restrict__ ba,     // [S]
                                                _Float16* __restrict__ hTf,
                                                _Float16* __restrict__ hTh,
                                                _Float16* __restrict__ hTl,
                                                int jparts) {
    __shared__ float w_lds[SS][192];      // 48KB
    __shared__ float a_lds[16][68];
    __shared__ float h_lds[16][68];
    __shared__ float zrh_lds[16][196];
    __shared__ float uzr_lds[16][132];
    __shared__ float rh_lds[16][68];

    const int n0 = blockIdx.x * 16;
    const int t = threadIdx.x;
    const int nl = t & 15;
    const int kg = t >> 4;

    {
        const int row = t >> 4, c4 = t & 15;
        float4 v = *(const float4*)(h + (size_t)(n0 + row) * SS + c4 * 4);
        *(float4*)&h_lds[row][c4 * 4] = v;
    }

    float zacc[12];
#pragma unroll
    for (int k = 0; k < 12; k++) zacc[k] = 0.0f;
    const int k0 = kg * 12;

    for (int e = 0; e < EE; e++) {
        __syncthreads();
        {
            const float4* wsrc = (const float4*)(W + (size_t)e * SS * 192);
            float4* wdst = (float4*)&w_lds[0][0];
#pragma unroll
            for (int r = 0; r < 12; r++) wdst[r * 256 + t] = wsrc[r * 256 + t];
        }
        {
            const int row = t >> 4, c4 = t & 15;
            const size_t base = ((size_t)e * NN + (n0 + row)) * SS + c4 * 4;
            float4 bv = *(const float4*)(ba + c4 * 4);
            float vx = bv.x, vy = bv.y, vz = bv.z, vw = bv.w;
            for (int p = 0; p < jparts; p++) {
                float4 pp = *(const float4*)(act_part + base + (size_t)p * EE * NN * SS);
                vx += pp.x; vy += pp.y; vz += pp.z; vw += pp.w;
            }
            *(float4*)&a_lds[row][c4 * 4] = make_float4(vx, vy, vz, vw);
        }
        __syncthreads();
#pragma unroll 8
        for (int s = 0; s < SS; s++) {
            const float av = a_lds[nl][s];
            const float4* wrow = (const float4*)&w_lds[s][k0];
            const float4 w0 = wrow[0], w1 = wrow[1], w2 = wrow[2];
            zacc[0] += av * w0.x; zacc[1] += av * w0.y; zacc[2]  += av * w0.z; zacc[3]  += av * w0.w;
            zacc[4] += av * w1.x; zacc[5] += av * w1.y; zacc[6]  += av * w1.z; zacc[7]  += av * w1.w;
            zacc[8] += av * w2.x; zacc[9] += av * w2.y; zacc[10] += av * w2.z; zacc[11] += av * w2.w;
        }
    }

    float uacc[8];
#pragma unroll
    for (int k = 0; k < 8; k++) uacc[k] = 0.0f;
#pragma unroll 4
    for (int j = 0; j < SS; j++) {
        const float hv = h_lds[nl][j];
        const float4* urow = (const float4*)(uz_ur + (size_t)j * 128 + kg * 8);
        const float4 u0 = urow[0], u1 = urow[1];
        uacc[0] += hv * u0.x; uacc[1] += hv * u0.y; uacc[2] += hv * u0.z; uacc[3] += hv * u0.w;
        uacc[4] += hv * u1.x; uacc[5] += hv * u1.y; uacc[6] += hv * u1.z; uacc[7] += hv * u1.w;
    }

    *(float4*)&zrh_lds[nl][k0]     = make_float4(zacc[0], zacc[1], zacc[2], zacc[3]);
    *(float4*)&zrh_lds[nl][k0 + 4] = make_float4(zacc[4], zacc[5], zacc[6], zacc[7]);
    *(float4*)&zrh_lds[nl][k0 + 8] = make_float4(zacc[8], zacc[9], zacc[10], zacc[11]);
    *(float4*)&uzr_lds[nl][kg * 8]     = make_float4(uacc[0], uacc[1], uacc[2], uacc[3]);
    *(float4*)&uzr_lds[nl][kg * 8 + 4] = make_float4(uacc[4], uacc[5], uacc[6], uacc[7]);
    __syncthreads();

    const int sg4 = kg * 4;
    const float4 wz = *(const float4*)&zrh_lds[nl][sg4];
    const float4 wr = *(const float4*)&zrh_lds[nl][64 + sg4];
    const float4 wh = *(const float4*)&zrh_lds[nl][128 + sg4];
    const float4 uz = *(const float4*)&uzr_lds[nl][sg4];
    const float4 ur = *(const float4*)&uzr_lds[nl][64 + sg4];
    const float4 hv4 = *(const float4*)&h_lds[nl][sg4];

    float z4[4], rh4[4];
    {
        const float wzv[4] = {wz.x, wz.y, wz.z, wz.w};
        const float wrv[4] = {wr.x, wr.y, wr.z, wr.w};
        const float uzv[4] = {uz.x, uz.y, uz.z, uz.w};
        const float urv[4] = {ur.x, ur.y, ur.z, ur.w};
        const float hvv[4] = {hv4.x, hv4.y, hv4.z, hv4.w};
#pragma unroll
        for (int k = 0; k < 4; k++) {
            z4[k] = sigf(wzv[k] + uzv[k]);
            const float r = sigf(wrv[k] + urv[k]);
            rh4[k] = r * hvv[k];
        }
    }
    *(float4*)&rh_lds[nl][sg4] = make_float4(rh4[0], rh4[1], rh4[2], rh4[3]);
    __syncthreads();

    float hacc[4];
#pragma unroll
    for (int k = 0; k < 4; k++) hacc[k] = 0.0f;
#pragma unroll 4
    for (int j = 0; j < SS; j++) {
        const float rhv = rh_lds[nl][j];
        const float4 u = *(const float4*)(uh + (size_t)j * SS + sg4);
        hacc[0] += rhv * u.x; hacc[1] += rhv * u.y; hacc[2] += rhv * u.z; hacc[3] += rhv * u.w;
    }

    {
        const float whv[4] = {wh.x, wh.y, wh.z, wh.w};
        const float hvv[4] = {hv4.x, hv4.y, hv4.z, hv4.w};
        float ov[4];
#pragma unroll
        for (int k = 0; k < 4; k++) {
            const float hh = tanhf(whv[k] + hacc[k]);
            ov[k] = (1.0f - z4[k]) * hvv[k] + z4[k] * hh;
        }
        const int n = n0 + nl;
        *(float4*)(h + (size_t)n * SS + sg4) = make_float4(ov[0], ov[1], ov[2], ov[3]);
#pragma unroll
        for (int k = 0; k < 4; k++) {
            _Float16 hi = (_Float16)ov[k];
            _Float16 lo = (_Float16)(ov[k] - (float)hi);
            if (hTf) {
                hTf[bslot(n, sg4 + k, 0)] = hi;
                hTf[bslot(n, sg4 + k, 1)] = lo;
            }
            if (hTh) {
                hTh[(size_t)(sg4 + k) * NN + n] = hi;
                hTl[(size_t)(sg4 + k) * NN + n] = lo;
            }
        }
    }
}

extern "C" void kernel_launch(void* const* d_in, const int* in_sizes, int n_in,
                              void* d_out, int out_size, void* d_ws, size_t ws_size,
                              hipStream_t stream) {
    const float* x    = (const float*)d_in[0];
    const float* edge = (const float*)d_in[1];
    const float* ba   = (const float*)d_in[2];
    const float* W    = (const float*)d_in[3];
    const float* uzur = (const float*)d_in[4];
    const float* uh   = (const float*)d_in[5];

    float* h = (float*)d_out;
    char*  wsb = (char*)d_ws;

    const size_t actB = (size_t)EE * NN * SS * sizeof(float);        // 6.29 MB
    const size_t hTfB = (size_t)NSG * 4 * 2 * 512 * sizeof(_Float16);// 1.0 MB (B fragments)
    const size_t hTBu = (size_t)SS * NN * sizeof(_Float16) * 2;      // 1.0 MB (fallback row-major)
    const size_t eTfB = (size_t)EE * NN * NN * 2 * sizeof(_Float16); // 402.7 MB
    const int jp = 4;
    const size_t needFull = eTfB + (size_t)jp * actB + hTfB;         // ~429 MB

    if (ws_size >= needFull) {
        _Float16* eTf = (_Float16*)wsb;
        float*    act = (float*)(wsb + eTfB);
        _Float16* hTf = (_Float16*)(wsb + eTfB + (size_t)jp * actB);
        const int jtot = NN / jp;

        k_init<<<NN / 16, 256, 0, stream>>>(x, h, hTf, nullptr, nullptr);

        // it = 0: act + pack fused (fp32 edge reads, writes 64n-tile eTf fragments)
        k_act_pack<<<dim3(NN / 64, EE, jp), 128, 0, stream>>>(edge, hTf, act, eTf, jtot);
        k_update<<<NN / 16, 256, 0, stream>>>(act, h, W, uzur, uh, ba, hTf, nullptr, nullptr, jp);

        for (int it = 1; it < ITERS; ++it) {
            k_act4w<<<dim3(NN / 64, EE, jp), 64, 0, stream>>>(eTf, hTf, act, jtot);
            k_update<<<NN / 16, 256, 0, stream>>>(act, h, W, uzur, uh, ba, hTf, nullptr, nullptr, jp);
        }
    } else {
        int jp2;
        bool use_mfma;
        if      (ws_size >= 4 * actB + hTBu) { jp2 = 4; use_mfma = true;  }
        else if (ws_size >= 2 * actB + hTBu) { jp2 = 2; use_mfma = true;  }
        else if (ws_size >= 1 * actB + hTBu) { jp2 = 1; use_mfma = true;  }
        else                                 { jp2 = 1; use_mfma = false; }

        float*     act = (float*)wsb;
        _Float16*  hTh = use_mfma ? (_Float16*)(wsb + (size_t)jp2 * actB) : nullptr;
        _Float16*  hTl = use_mfma ? (_Float16*)(wsb + (size_t)jp2 * actB) + (size_t)SS * NN : nullptr;
        const int jtot = NN / jp2;

        k_init<<<NN / 16, 256, 0, stream>>>(x, h, nullptr, hTh, hTl);
        for (int it = 0; it < ITERS; ++it) {
            if (use_mfma) {
                k_act_mfma<<<dim3(NN / 64, EE, jp2), 128, 0, stream>>>(edge, hTh, hTl, act, jtot);
            } else {
                k_act<<<dim3(NN / BN, EE, jp2), 128, 0, stream>>>(edge, h, act, jtot);
            }
            k_update<<<NN / 16, 256, 0, stream>>>(act, h, W, uzur, uh, ba, nullptr, hTh, hTl, jp2);
        }
    }
}